// Round 1
// baseline (1309.162 us; speedup 1.0000x reference)
//
#include <hip/hip_runtime.h>
#include <math.h>

// Problem constants
#define NREL 499   // 2*MAX_LEN-1

// ============================================================================
// GEMM: A[4096x512] @ W[512x512] + bias -> out, tile 64x64, Ktile 64,
// 256 threads, 4x4 micro-tile per thread.
// MODE 0: plain row-major out [4096][512]         (output projection)
// MODE 1: out as Qt/Kt head-split d-major [bh][64][2048]
// MODE 2: out as V head-split row-major [bh][2048][64]
// ============================================================================
template <int MODE>
__global__ __launch_bounds__(256) void gemm512(const float* __restrict__ A,
                                               const float* __restrict__ W,
                                               const float* __restrict__ bias,
                                               float* __restrict__ out) {
  __shared__ float As[64][68];  // As[k][i]  (transposed A tile, padded)
  __shared__ float Bs[64][68];  // Bs[k][n]
  const int t = threadIdx.x;
  const int tx = t & 15, ty = t >> 4;
  const int i0 = blockIdx.y * 64;
  const int n0 = blockIdx.x * 64;
  float acc[4][4] = {};
  for (int kt = 0; kt < 512; kt += 64) {
#pragma unroll
    for (int s = 0; s < 4; ++s) {
      int idx = t + s * 256;          // 0..1023
      int r = idx >> 4;               // 0..63
      int c4 = (idx & 15) << 2;       // 0,4,..,60
      float4 a = *(const float4*)(A + (size_t)(i0 + r) * 512 + kt + c4);
      As[c4 + 0][r] = a.x; As[c4 + 1][r] = a.y;
      As[c4 + 2][r] = a.z; As[c4 + 3][r] = a.w;
      float4 b = *(const float4*)(W + (size_t)(kt + r) * 512 + n0 + c4);
      *(float4*)&Bs[r][c4] = b;
    }
    __syncthreads();
#pragma unroll
    for (int k = 0; k < 64; ++k) {
      float4 a4 = *(const float4*)&As[k][ty << 2];
      float4 b4 = *(const float4*)&Bs[k][tx << 2];
      float av[4] = {a4.x, a4.y, a4.z, a4.w};
      float bv[4] = {b4.x, b4.y, b4.z, b4.w};
#pragma unroll
      for (int ii = 0; ii < 4; ++ii)
#pragma unroll
        for (int jj = 0; jj < 4; ++jj) acc[ii][jj] += av[ii] * bv[jj];
    }
    __syncthreads();
  }
  float4 bb = *(const float4*)(bias + n0 + (tx << 2));
  float bv[4] = {bb.x, bb.y, bb.z, bb.w};
#pragma unroll
  for (int ii = 0; ii < 4; ++ii) {
    int i = i0 + (ty << 2) + ii;
    if (MODE == 0) {
      float4 o = make_float4(acc[ii][0] + bv[0], acc[ii][1] + bv[1],
                             acc[ii][2] + bv[2], acc[ii][3] + bv[3]);
      *(float4*)(out + (size_t)i * 512 + n0 + (tx << 2)) = o;
    } else if (MODE == 1) {
      int b = i >> 11, l = i & 2047;
#pragma unroll
      for (int jj = 0; jj < 4; ++jj) {
        int c = n0 + (tx << 2) + jj;
        int h = c >> 6, d = c & 63;
        out[(size_t)((b * 8 + h) * 64 + d) * 2048 + l] = acc[ii][jj] + bv[jj];
      }
    } else {
      int b = i >> 11, l = i & 2047;
      int c = n0 + (tx << 2);
      int h = c >> 6, d = c & 63;
      float4 o = make_float4(acc[ii][0] + bv[0], acc[ii][1] + bv[1],
                             acc[ii][2] + bv[2], acc[ii][3] + bv[3]);
      *(float4*)(out + (size_t)((b * 8 + h) * 2048 + l) * 64 + d) = o;
    }
  }
}

// ============================================================================
// qrel[bh][i][r] = sum_d Qt[bh][d][i] * rel[r][d]
// grid: (8 r-tiles, 32 i-tiles, 16 bh); one 64x64x64 GEMM tile per block.
// ============================================================================
__global__ __launch_bounds__(256) void qrel_kernel(const float* __restrict__ Qt,
                                                   const float* __restrict__ rel,
                                                   float* __restrict__ qrel) {
  __shared__ float Qs[64][64];  // [d][i]
  __shared__ float Rs[64][68];  // [d][r] (transposed rel tile, padded)
  const int t = threadIdx.x;
  const int tx = t & 15, ty = t >> 4;
  const int r0 = blockIdx.x * 64;
  const int i0 = blockIdx.y * 64;
  const int bh = blockIdx.z;
  const float* Qb = Qt + (size_t)bh * 64 * 2048;
#pragma unroll
  for (int s = 0; s < 4; ++s) {
    int idx = t + s * 256;
    int d = idx >> 4;
    int c4 = (idx & 15) << 2;
    *(float4*)&Qs[d][c4] = *(const float4*)(Qb + (size_t)d * 2048 + i0 + c4);
    int rr = d;  // same (row, chunk) mapping reused for the rel tile
    int rc = min(r0 + rr, NREL - 1);
    float4 g = *(const float4*)(rel + (size_t)rc * 64 + c4);
    Rs[c4 + 0][rr] = g.x; Rs[c4 + 1][rr] = g.y;
    Rs[c4 + 2][rr] = g.z; Rs[c4 + 3][rr] = g.w;
  }
  __syncthreads();
  float acc[4][4] = {};
#pragma unroll
  for (int d = 0; d < 64; ++d) {
    float4 a4 = *(const float4*)&Qs[d][ty << 2];
    float4 b4 = *(const float4*)&Rs[d][tx << 2];
    float av[4] = {a4.x, a4.y, a4.z, a4.w};
    float bv[4] = {b4.x, b4.y, b4.z, b4.w};
#pragma unroll
    for (int ii = 0; ii < 4; ++ii)
#pragma unroll
      for (int jj = 0; jj < 4; ++jj) acc[ii][jj] += av[ii] * bv[jj];
  }
#pragma unroll
  for (int ii = 0; ii < 4; ++ii) {
    int i = i0 + (ty << 2) + ii;
#pragma unroll
    for (int jj = 0; jj < 4; ++jj) {
      int r = r0 + (tx << 2) + jj;
      if (r < NREL) qrel[((size_t)bh * 2048 + i) * NREL + r] = acc[ii][jj];
    }
  }
}

// ============================================================================
// Flash attention: one block per (bh, i-tile of 64). Loops 32 j-tiles.
// S = (Qt_i^T Kt_j)/8 + qrel-gathered bias, key-pad mask, online softmax,
// O += P V. P reuses the K LDS buffer (K dead after S-GEMM).
// ============================================================================
__global__ __launch_bounds__(256) void flash_attn(
    const float* __restrict__ Qt, const float* __restrict__ Kt,
    const float* __restrict__ V, const float* __restrict__ qrel,
    const int* __restrict__ mask, float* __restrict__ attn) {
  __shared__ float Qs[64][64];  // [d][i]
  __shared__ float Ks[64][64];  // [d][j], reused as P[j][i] after S-GEMM
  __shared__ float Vs[64][64];  // [j][d]
  const int t = threadIdx.x;
  const int tx = t & 15, ty = t >> 4;
  const int i0 = blockIdx.x * 64;
  const int bh = blockIdx.y;
  const int b = bh >> 3, h = bh & 7;
  const float* Qb = Qt + (size_t)bh * 64 * 2048;
  const float* Kb = Kt + (size_t)bh * 64 * 2048;
  const float* Vb = V + (size_t)bh * 2048 * 64;
  const float* qrl = qrel + (size_t)bh * 2048 * NREL;
  const int* mb = mask + b * 2048;

#pragma unroll
  for (int s = 0; s < 4; ++s) {
    int idx = t + s * 256;
    int d = idx >> 4, c4 = (idx & 15) << 2;
    *(float4*)&Qs[d][c4] = *(const float4*)(Qb + (size_t)d * 2048 + i0 + c4);
  }

  float m_i[4], l_i[4];
  float o_acc[4][4] = {};
#pragma unroll
  for (int ii = 0; ii < 4; ++ii) { m_i[ii] = -INFINITY; l_i[ii] = 0.f; }

  for (int j0 = 0; j0 < 2048; j0 += 64) {
#pragma unroll
    for (int s = 0; s < 4; ++s) {
      int idx = t + s * 256;
      int r = idx >> 4, c4 = (idx & 15) << 2;
      *(float4*)&Ks[r][c4] = *(const float4*)(Kb + (size_t)r * 2048 + j0 + c4);
      *(float4*)&Vs[r][c4] = *(const float4*)(Vb + (size_t)(j0 + r) * 64 + c4);
    }
    __syncthreads();

    // S tile
    float s_t[4][4] = {};
#pragma unroll
    for (int d = 0; d < 64; ++d) {
      float4 a4 = *(const float4*)&Qs[d][ty << 2];
      float4 b4 = *(const float4*)&Ks[d][tx << 2];
      float av[4] = {a4.x, a4.y, a4.z, a4.w};
      float bv[4] = {b4.x, b4.y, b4.z, b4.w};
#pragma unroll
      for (int ii = 0; ii < 4; ++ii)
#pragma unroll
        for (int jj = 0; jj < 4; ++jj) s_t[ii][jj] += av[ii] * bv[jj];
    }

    // bias + mask
    int4 mk4 = *(const int4*)(mb + j0 + (tx << 2));
    int mk[4] = {mk4.x, mk4.y, mk4.z, mk4.w};
#pragma unroll
    for (int ii = 0; ii < 4; ++ii) {
      int i = i0 + (ty << 2) + ii;
#pragma unroll
      for (int jj = 0; jj < 4; ++jj) {
        int j = j0 + (tx << 2) + jj;
        int r = j - i + (NREL / 2);
        r = max(0, min(NREL - 1, r));
        float sc = s_t[ii][jj] * 0.125f + qrl[(size_t)i * NREL + r];
        s_t[ii][jj] = (mk[jj] == 0) ? -1e10f : sc;
      }
    }

    // online softmax (row groups = 16 lanes sharing ty within a wave)
    float al[4];
#pragma unroll
    for (int ii = 0; ii < 4; ++ii) {
      float mx = fmaxf(fmaxf(s_t[ii][0], s_t[ii][1]),
                       fmaxf(s_t[ii][2], s_t[ii][3]));
#pragma unroll
      for (int w = 1; w < 16; w <<= 1) mx = fmaxf(mx, __shfl_xor(mx, w, 16));
      float mnew = fmaxf(m_i[ii], mx);
      al[ii] = __expf(m_i[ii] - mnew);
      m_i[ii] = mnew;
      float sum = 0.f;
#pragma unroll
      for (int jj = 0; jj < 4; ++jj) {
        float p = __expf(s_t[ii][jj] - mnew);
        s_t[ii][jj] = p;
        sum += p;
      }
#pragma unroll
      for (int w = 1; w < 16; w <<= 1) sum += __shfl_xor(sum, w, 16);
      l_i[ii] = l_i[ii] * al[ii] + sum;
#pragma unroll
      for (int jj = 0; jj < 4; ++jj) o_acc[ii][jj] *= al[ii];
    }

    __syncthreads();  // all S-GEMM reads of Ks done before P overwrites it
#pragma unroll
    for (int jj = 0; jj < 4; ++jj) {
      float4 pv = make_float4(s_t[0][jj], s_t[1][jj], s_t[2][jj], s_t[3][jj]);
      *(float4*)&Ks[(tx << 2) + jj][ty << 2] = pv;  // Ks now holds P[j][i]
    }
    __syncthreads();

    // O += P V
#pragma unroll
    for (int j = 0; j < 64; ++j) {
      float4 a4 = *(const float4*)&Ks[j][ty << 2];   // P[j][i..]
      float4 b4 = *(const float4*)&Vs[j][tx << 2];   // V[j][d..]
      float av[4] = {a4.x, a4.y, a4.z, a4.w};
      float bv[4] = {b4.x, b4.y, b4.z, b4.w};
#pragma unroll
      for (int ii = 0; ii < 4; ++ii)
#pragma unroll
        for (int jj = 0; jj < 4; ++jj) o_acc[ii][jj] += av[ii] * bv[jj];
    }
    __syncthreads();  // PV done before next staging overwrites Ks/Vs
  }

  // normalize + write attn[b][i][h*64+d]
#pragma unroll
  for (int ii = 0; ii < 4; ++ii) {
    int i = i0 + (ty << 2) + ii;
    float inv = 1.0f / l_i[ii];
    float4 o = make_float4(o_acc[ii][0] * inv, o_acc[ii][1] * inv,
                           o_acc[ii][2] * inv, o_acc[ii][3] * inv);
    *(float4*)(attn + (size_t)(b * 2048 + i) * 512 + h * 64 + (tx << 2)) = o;
  }
}

// ============================================================================
extern "C" void kernel_launch(void* const* d_in, const int* in_sizes, int n_in,
                              void* d_out, int out_size, void* d_ws,
                              size_t ws_size, hipStream_t stream) {
  const float* query = (const float*)d_in[0];
  const float* key   = (const float*)d_in[1];
  const float* value = (const float*)d_in[2];
  const int*   mask  = (const int*)d_in[3];
  const float* Wq = (const float*)d_in[4];
  const float* bq = (const float*)d_in[5];
  const float* Wk = (const float*)d_in[6];
  const float* bk = (const float*)d_in[7];
  const float* Wv = (const float*)d_in[8];
  const float* bv = (const float*)d_in[9];
  const float* Wo = (const float*)d_in[10];
  const float* bo = (const float*)d_in[11];
  const float* rel = (const float*)d_in[12];

  float* ws = (float*)d_ws;
  float* Qt   = ws;                                   // [16][64][2048]
  float* Kt   = Qt + (size_t)16 * 64 * 2048;          // [16][64][2048]
  float* Vw   = Kt + (size_t)16 * 64 * 2048;          // [16][2048][64]
  float* qrel = Vw + (size_t)16 * 2048 * 64;          // [16][2048][499]
  float* attn = qrel + (size_t)16 * 2048 * NREL;      // [4096][512]
  float* out = (float*)d_out;

  dim3 bb(256);
  dim3 gg(8, 64);
  hipLaunchKernelGGL((gemm512<1>), gg, bb, 0, stream, query, Wq, bq, Qt);
  hipLaunchKernelGGL((gemm512<1>), gg, bb, 0, stream, key, Wk, bk, Kt);
  hipLaunchKernelGGL((gemm512<2>), gg, bb, 0, stream, value, Wv, bv, Vw);
  hipLaunchKernelGGL(qrel_kernel, dim3(8, 32, 16), bb, 0, stream, Qt, rel, qrel);
  hipLaunchKernelGGL(flash_attn, dim3(32, 16), bb, 0, stream, Qt, Kt, Vw, qrel,
                     mask, attn);
  hipLaunchKernelGGL((gemm512<0>), gg, bb, 0, stream, attn, Wo, bo, out);
}

// Round 2
// 575.111 us; speedup vs baseline: 2.2764x; 2.2764x over previous
//
#include <hip/hip_runtime.h>
#include <math.h>

// Problem constants
#define NREL 499        // 2*MAX_LEN-1
#define NREL_PAD 500    // row stride for qrel (2000 B, 16-B aligned)

// ============================================================================
// GEMM: A[4096x512] @ W[512x512] + bias -> out, tile 64x64, Ktile 64,
// 256 threads, 4x4 micro-tile per thread.
// MODE 0: plain row-major out [4096][512]         (output projection)
// MODE 1: out as Qt/Kt head-split d-major [bh][64][2048] (LDS-transposed epilogue)
// MODE 2: out as V head-split row-major [bh][2048][64]
// ============================================================================
template <int MODE>
__global__ __launch_bounds__(256) void gemm512(const float* __restrict__ A,
                                               const float* __restrict__ W,
                                               const float* __restrict__ bias,
                                               float* __restrict__ out) {
  __shared__ float As[64][68];  // As[k][i]  (transposed A tile, padded)
  __shared__ float Bs[64][68];  // Bs[k][n]; reused as transpose buffer (MODE 1)
  const int t = threadIdx.x;
  const int tx = t & 15, ty = t >> 4;
  const int i0 = blockIdx.y * 64;
  const int n0 = blockIdx.x * 64;
  float acc[4][4] = {};
  for (int kt = 0; kt < 512; kt += 64) {
#pragma unroll
    for (int s = 0; s < 4; ++s) {
      int idx = t + s * 256;          // 0..1023
      int r = idx >> 4;               // 0..63
      int c4 = (idx & 15) << 2;       // 0,4,..,60
      float4 a = *(const float4*)(A + (size_t)(i0 + r) * 512 + kt + c4);
      As[c4 + 0][r] = a.x; As[c4 + 1][r] = a.y;
      As[c4 + 2][r] = a.z; As[c4 + 3][r] = a.w;
      float4 b = *(const float4*)(W + (size_t)(kt + r) * 512 + n0 + c4);
      *(float4*)&Bs[r][c4] = b;
    }
    __syncthreads();
#pragma unroll
    for (int k = 0; k < 64; ++k) {
      float4 a4 = *(const float4*)&As[k][ty << 2];
      float4 b4 = *(const float4*)&Bs[k][tx << 2];
      float av[4] = {a4.x, a4.y, a4.z, a4.w};
      float bv[4] = {b4.x, b4.y, b4.z, b4.w};
#pragma unroll
      for (int ii = 0; ii < 4; ++ii)
#pragma unroll
        for (int jj = 0; jj < 4; ++jj) acc[ii][jj] += av[ii] * bv[jj];
    }
    __syncthreads();
  }
  float4 bb = *(const float4*)(bias + n0 + (tx << 2));
  float bv[4] = {bb.x, bb.y, bb.z, bb.w};
  if (MODE == 1) {
    // LDS transpose: Bs[c_local][i_local] = acc+bias, then coalesced writes
    // along l into Qt/Kt [bh][d][2048].
#pragma unroll
    for (int jj = 0; jj < 4; ++jj)
#pragma unroll
      for (int ii = 0; ii < 4; ++ii)
        Bs[(tx << 2) + jj][(ty << 2) + ii] = acc[ii][jj] + bv[jj];
    __syncthreads();
    const int b = i0 >> 11, l0 = i0 & 2047;
#pragma unroll
    for (int s = 0; s < 4; ++s) {
      int idx = t + s * 256;
      int row = idx >> 4;             // c_local 0..63
      int col4 = (idx & 15) << 2;     // i_local
      int c = n0 + row;
      int h = c >> 6, d = c & 63;
      float4 o = *(const float4*)&Bs[row][col4];
      *(float4*)(out + (size_t)((b * 8 + h) * 64 + d) * 2048 + l0 + col4) = o;
    }
    return;
  }
#pragma unroll
  for (int ii = 0; ii < 4; ++ii) {
    int i = i0 + (ty << 2) + ii;
    if (MODE == 0) {
      float4 o = make_float4(acc[ii][0] + bv[0], acc[ii][1] + bv[1],
                             acc[ii][2] + bv[2], acc[ii][3] + bv[3]);
      *(float4*)(out + (size_t)i * 512 + n0 + (tx << 2)) = o;
    } else {  // MODE 2
      int b = i >> 11, l = i & 2047;
      int c = n0 + (tx << 2);
      int h = c >> 6, d = c & 63;
      float4 o = make_float4(acc[ii][0] + bv[0], acc[ii][1] + bv[1],
                             acc[ii][2] + bv[2], acc[ii][3] + bv[3]);
      *(float4*)(out + (size_t)((b * 8 + h) * 2048 + l) * 64 + d) = o;
    }
  }
}

// ============================================================================
// qrel[bh][i][r] = sum_d Qt[bh][d][i] * rel[r][d], row stride NREL_PAD.
// One block per (i-tile of 64, bh); loops all 8 r-tiles reusing the Q tile.
// Guard-free float4 stores: last valid start r=496 covers r<=499 exactly.
// ============================================================================
__global__ __launch_bounds__(256) void qrel_kernel(const float* __restrict__ Qt,
                                                   const float* __restrict__ rel,
                                                   float* __restrict__ qrel) {
  __shared__ float Qs[64][64];  // [d][i]
  __shared__ float Rs[64][68];  // [d][r] (transposed rel tile, padded)
  const int t = threadIdx.x;
  const int tx = t & 15, ty = t >> 4;
  const int i0 = blockIdx.x * 64;
  const int bh = blockIdx.y;
  const float* Qb = Qt + (size_t)bh * 64 * 2048;
#pragma unroll
  for (int s = 0; s < 4; ++s) {
    int idx = t + s * 256;
    int d = idx >> 4;
    int c4 = (idx & 15) << 2;
    *(float4*)&Qs[d][c4] = *(const float4*)(Qb + (size_t)d * 2048 + i0 + c4);
  }
  for (int r0 = 0; r0 < 512; r0 += 64) {
    __syncthreads();  // previous iter's Rs readers done (also covers Qs 1st time)
#pragma unroll
    for (int s = 0; s < 4; ++s) {
      int idx = t + s * 256;
      int rr = idx >> 4;
      int c4 = (idx & 15) << 2;
      int rc = min(r0 + rr, NREL - 1);
      float4 g = *(const float4*)(rel + (size_t)rc * 64 + c4);
      Rs[c4 + 0][rr] = g.x; Rs[c4 + 1][rr] = g.y;
      Rs[c4 + 2][rr] = g.z; Rs[c4 + 3][rr] = g.w;
    }
    __syncthreads();
    float acc[4][4] = {};
#pragma unroll
    for (int d = 0; d < 64; ++d) {
      float4 a4 = *(const float4*)&Qs[d][ty << 2];
      float4 b4 = *(const float4*)&Rs[d][tx << 2];
      float av[4] = {a4.x, a4.y, a4.z, a4.w};
      float bv[4] = {b4.x, b4.y, b4.z, b4.w};
#pragma unroll
      for (int ii = 0; ii < 4; ++ii)
#pragma unroll
        for (int jj = 0; jj < 4; ++jj) acc[ii][jj] += av[ii] * bv[jj];
    }
    int r = r0 + (tx << 2);
    if (r <= NREL_PAD - 4) {
#pragma unroll
      for (int ii = 0; ii < 4; ++ii) {
        int i = i0 + (ty << 2) + ii;
        float4 o = make_float4(acc[ii][0], acc[ii][1], acc[ii][2], acc[ii][3]);
        *(float4*)(qrel + ((size_t)bh * 2048 + i) * NREL_PAD + r) = o;
      }
    }
  }
}

// ============================================================================
// Flash attention: one block per (bh, i-tile of 64). Loops 32 j-tiles.
// S = (Qt_i^T Kt_j)/8 + qrel-gathered bias, key-pad mask, online softmax,
// O += P V. P reuses the K LDS buffer (K dead after S-GEMM).
// ============================================================================
__global__ __launch_bounds__(256) void flash_attn(
    const float* __restrict__ Qt, const float* __restrict__ Kt,
    const float* __restrict__ V, const float* __restrict__ qrel,
    const int* __restrict__ mask, float* __restrict__ attn) {
  __shared__ float Qs[64][64];  // [d][i]
  __shared__ float Ks[64][64];  // [d][j], reused as P[j][i] after S-GEMM
  __shared__ float Vs[64][64];  // [j][d]
  const int t = threadIdx.x;
  const int tx = t & 15, ty = t >> 4;
  const int i0 = blockIdx.x * 64;
  const int bh = blockIdx.y;
  const int b = bh >> 3, h = bh & 7;
  const float* Qb = Qt + (size_t)bh * 64 * 2048;
  const float* Kb = Kt + (size_t)bh * 64 * 2048;
  const float* Vb = V + (size_t)bh * 2048 * 64;
  const float* qrl = qrel + (size_t)bh * 2048 * NREL_PAD;
  const int* mb = mask + b * 2048;

#pragma unroll
  for (int s = 0; s < 4; ++s) {
    int idx = t + s * 256;
    int d = idx >> 4, c4 = (idx & 15) << 2;
    *(float4*)&Qs[d][c4] = *(const float4*)(Qb + (size_t)d * 2048 + i0 + c4);
  }

  float m_i[4], l_i[4];
  float o_acc[4][4] = {};
#pragma unroll
  for (int ii = 0; ii < 4; ++ii) { m_i[ii] = -INFINITY; l_i[ii] = 0.f; }

  for (int j0 = 0; j0 < 2048; j0 += 64) {
#pragma unroll
    for (int s = 0; s < 4; ++s) {
      int idx = t + s * 256;
      int r = idx >> 4, c4 = (idx & 15) << 2;
      *(float4*)&Ks[r][c4] = *(const float4*)(Kb + (size_t)r * 2048 + j0 + c4);
      *(float4*)&Vs[r][c4] = *(const float4*)(Vb + (size_t)(j0 + r) * 64 + c4);
    }
    __syncthreads();

    // S tile
    float s_t[4][4] = {};
#pragma unroll
    for (int d = 0; d < 64; ++d) {
      float4 a4 = *(const float4*)&Qs[d][ty << 2];
      float4 b4 = *(const float4*)&Ks[d][tx << 2];
      float av[4] = {a4.x, a4.y, a4.z, a4.w};
      float bv[4] = {b4.x, b4.y, b4.z, b4.w};
#pragma unroll
      for (int ii = 0; ii < 4; ++ii)
#pragma unroll
        for (int jj = 0; jj < 4; ++jj) s_t[ii][jj] += av[ii] * bv[jj];
    }

    // bias + mask
    int4 mk4 = *(const int4*)(mb + j0 + (tx << 2));
    int mk[4] = {mk4.x, mk4.y, mk4.z, mk4.w};
#pragma unroll
    for (int ii = 0; ii < 4; ++ii) {
      int i = i0 + (ty << 2) + ii;
#pragma unroll
      for (int jj = 0; jj < 4; ++jj) {
        int j = j0 + (tx << 2) + jj;
        int r = j - i + (NREL / 2);
        r = max(0, min(NREL - 1, r));
        float sc = s_t[ii][jj] * 0.125f + qrl[(size_t)i * NREL_PAD + r];
        s_t[ii][jj] = (mk[jj] == 0) ? -1e10f : sc;
      }
    }

    // online softmax (row groups = 16 lanes sharing ty within a wave)
    float al[4];
#pragma unroll
    for (int ii = 0; ii < 4; ++ii) {
      float mx = fmaxf(fmaxf(s_t[ii][0], s_t[ii][1]),
                       fmaxf(s_t[ii][2], s_t[ii][3]));
#pragma unroll
      for (int w = 1; w < 16; w <<= 1) mx = fmaxf(mx, __shfl_xor(mx, w, 16));
      float mnew = fmaxf(m_i[ii], mx);
      al[ii] = __expf(m_i[ii] - mnew);
      m_i[ii] = mnew;
      float sum = 0.f;
#pragma unroll
      for (int jj = 0; jj < 4; ++jj) {
        float p = __expf(s_t[ii][jj] - mnew);
        s_t[ii][jj] = p;
        sum += p;
      }
#pragma unroll
      for (int w = 1; w < 16; w <<= 1) sum += __shfl_xor(sum, w, 16);
      l_i[ii] = l_i[ii] * al[ii] + sum;
#pragma unroll
      for (int jj = 0; jj < 4; ++jj) o_acc[ii][jj] *= al[ii];
    }

    __syncthreads();  // all S-GEMM reads of Ks done before P overwrites it
#pragma unroll
    for (int jj = 0; jj < 4; ++jj) {
      float4 pv = make_float4(s_t[0][jj], s_t[1][jj], s_t[2][jj], s_t[3][jj]);
      *(float4*)&Ks[(tx << 2) + jj][ty << 2] = pv;  // Ks now holds P[j][i]
    }
    __syncthreads();

    // O += P V
#pragma unroll
    for (int j = 0; j < 64; ++j) {
      float4 a4 = *(const float4*)&Ks[j][ty << 2];   // P[j][i..]
      float4 b4 = *(const float4*)&Vs[j][tx << 2];   // V[j][d..]
      float av[4] = {a4.x, a4.y, a4.z, a4.w};
      float bv[4] = {b4.x, b4.y, b4.z, b4.w};
#pragma unroll
      for (int ii = 0; ii < 4; ++ii)
#pragma unroll
        for (int jj = 0; jj < 4; ++jj) o_acc[ii][jj] += av[ii] * bv[jj];
    }
    __syncthreads();  // PV done before next staging overwrites Ks/Vs
  }

  // normalize + write attn[b][i][h*64+d]
#pragma unroll
  for (int ii = 0; ii < 4; ++ii) {
    int i = i0 + (ty << 2) + ii;
    float inv = 1.0f / l_i[ii];
    float4 o = make_float4(o_acc[ii][0] * inv, o_acc[ii][1] * inv,
                           o_acc[ii][2] * inv, o_acc[ii][3] * inv);
    *(float4*)(attn + (size_t)(b * 2048 + i) * 512 + h * 64 + (tx << 2)) = o;
  }
}

// ============================================================================
extern "C" void kernel_launch(void* const* d_in, const int* in_sizes, int n_in,
                              void* d_out, int out_size, void* d_ws,
                              size_t ws_size, hipStream_t stream) {
  const float* query = (const float*)d_in[0];
  const float* key   = (const float*)d_in[1];
  const float* value = (const float*)d_in[2];
  const int*   mask  = (const int*)d_in[3];
  const float* Wq = (const float*)d_in[4];
  const float* bq = (const float*)d_in[5];
  const float* Wk = (const float*)d_in[6];
  const float* bk = (const float*)d_in[7];
  const float* Wv = (const float*)d_in[8];
  const float* bv = (const float*)d_in[9];
  const float* Wo = (const float*)d_in[10];
  const float* bo = (const float*)d_in[11];
  const float* rel = (const float*)d_in[12];

  float* ws = (float*)d_ws;
  float* Qt   = ws;                                   // [16][64][2048]
  float* Kt   = Qt + (size_t)16 * 64 * 2048;          // [16][64][2048]
  float* Vw   = Kt + (size_t)16 * 64 * 2048;          // [16][2048][64]
  float* qrel = Vw + (size_t)16 * 2048 * 64;          // [16][2048][NREL_PAD]
  float* attn = qrel + (size_t)16 * 2048 * NREL_PAD;  // [4096][512]
  float* out = (float*)d_out;

  dim3 bb(256);
  dim3 gg(8, 64);
  hipLaunchKernelGGL((gemm512<1>), gg, bb, 0, stream, query, Wq, bq, Qt);
  hipLaunchKernelGGL((gemm512<1>), gg, bb, 0, stream, key, Wk, bk, Kt);
  hipLaunchKernelGGL((gemm512<2>), gg, bb, 0, stream, value, Wv, bv, Vw);
  hipLaunchKernelGGL(qrel_kernel, dim3(32, 16), bb, 0, stream, Qt, rel, qrel);
  hipLaunchKernelGGL(flash_attn, dim3(32, 16), bb, 0, stream, Qt, Kt, Vw, qrel,
                     mask, attn);
  hipLaunchKernelGGL((gemm512<0>), gg, bb, 0, stream, attn, Wo, bo, out);
}

// Round 3
// 435.925 us; speedup vs baseline: 3.0032x; 1.3193x over previous
//
#include <hip/hip_runtime.h>
#include <math.h>

// Problem constants
#define NREL 499        // 2*MAX_LEN-1
#define NREL_PAD 500    // row stride for qrel (2000 B, 16-B aligned)
#define LDB 72          // bf16 LDS row stride (144 B): b128 frag reads 2-way-free

typedef __attribute__((ext_vector_type(8))) short bf16x8;
typedef __attribute__((ext_vector_type(4))) float f32x4;

__device__ __forceinline__ float bf2f(ushort x) {
  union { unsigned u; float f; } v; v.u = ((unsigned)x) << 16; return v.f;
}
__device__ __forceinline__ ushort f2bf(float x) {
  union { float f; unsigned u; } v; v.f = x;
  return (ushort)((v.u + 0x8000u) >> 16);  // round-half-up, half-ulp bias ok
}

// ============================================================================
// GEMM: A[4096x512] @ W[512x512] + bias -> out, fp32 VALU, tile 64x64.
// MODE 0: fp32 row-major out [4096][512]                (output projection)
// MODE 1: bf16 transposed head-split [bh][64(d)][2048]  (V)
// MODE 2: bf16 row-major head-split [bh][2048][64]      (Q, K)
// ============================================================================
template <int MODE>
__global__ __launch_bounds__(256) void gemm512(const float* __restrict__ A,
                                               const float* __restrict__ W,
                                               const float* __restrict__ bias,
                                               void* __restrict__ outv) {
  __shared__ float As[64][68];  // As[k][i]  (transposed A tile, padded)
  __shared__ float Bs[64][68];  // Bs[k][n]; reused as transpose buffer (MODE 1)
  const int t = threadIdx.x;
  const int tx = t & 15, ty = t >> 4;
  const int i0 = blockIdx.y * 64;
  const int n0 = blockIdx.x * 64;
  float acc[4][4] = {};
  for (int kt = 0; kt < 512; kt += 64) {
#pragma unroll
    for (int s = 0; s < 4; ++s) {
      int idx = t + s * 256;          // 0..1023
      int r = idx >> 4;               // 0..63
      int c4 = (idx & 15) << 2;       // 0,4,..,60
      float4 a = *(const float4*)(A + (size_t)(i0 + r) * 512 + kt + c4);
      As[c4 + 0][r] = a.x; As[c4 + 1][r] = a.y;
      As[c4 + 2][r] = a.z; As[c4 + 3][r] = a.w;
      float4 b = *(const float4*)(W + (size_t)(kt + r) * 512 + n0 + c4);
      *(float4*)&Bs[r][c4] = b;
    }
    __syncthreads();
#pragma unroll
    for (int k = 0; k < 64; ++k) {
      float4 a4 = *(const float4*)&As[k][ty << 2];
      float4 b4 = *(const float4*)&Bs[k][tx << 2];
      float av[4] = {a4.x, a4.y, a4.z, a4.w};
      float bv[4] = {b4.x, b4.y, b4.z, b4.w};
#pragma unroll
      for (int ii = 0; ii < 4; ++ii)
#pragma unroll
        for (int jj = 0; jj < 4; ++jj) acc[ii][jj] += av[ii] * bv[jj];
    }
    __syncthreads();
  }
  float4 bb = *(const float4*)(bias + n0 + (tx << 2));
  float bv[4] = {bb.x, bb.y, bb.z, bb.w};
  if (MODE == 1) {
    // LDS transpose then coalesced bf16 writes along l into Vt [bh][d][2048].
#pragma unroll
    for (int jj = 0; jj < 4; ++jj)
#pragma unroll
      for (int ii = 0; ii < 4; ++ii)
        Bs[(tx << 2) + jj][(ty << 2) + ii] = acc[ii][jj] + bv[jj];
    __syncthreads();
    ushort* out = (ushort*)outv;
    const int b = i0 >> 11, l0 = i0 & 2047;
    const int h = n0 >> 6;
#pragma unroll
    for (int s = 0; s < 4; ++s) {
      int idx = t + s * 256;
      int row = idx >> 4;             // d 0..63
      int col4 = (idx & 15) << 2;     // l_local
      float4 o = *(const float4*)&Bs[row][col4];
      ushort4 u = make_ushort4(f2bf(o.x), f2bf(o.y), f2bf(o.z), f2bf(o.w));
      *(ushort4*)(out + (size_t)((b * 8 + h) * 64 + row) * 2048 + l0 + col4) = u;
    }
    return;
  }
#pragma unroll
  for (int ii = 0; ii < 4; ++ii) {
    int i = i0 + (ty << 2) + ii;
    if (MODE == 0) {
      float* out = (float*)outv;
      float4 o = make_float4(acc[ii][0] + bv[0], acc[ii][1] + bv[1],
                             acc[ii][2] + bv[2], acc[ii][3] + bv[3]);
      *(float4*)(out + (size_t)i * 512 + n0 + (tx << 2)) = o;
    } else {  // MODE 2: bf16 row-major [bh][l][64]
      ushort* out = (ushort*)outv;
      int b = i >> 11, l = i & 2047;
      int c = n0 + (tx << 2);
      int h = c >> 6, d = c & 63;
      ushort4 u = make_ushort4(f2bf(acc[ii][0] + bv[0]), f2bf(acc[ii][1] + bv[1]),
                               f2bf(acc[ii][2] + bv[2]), f2bf(acc[ii][3] + bv[3]));
      *(ushort4*)(out + ((size_t)(b * 8 + h) * 2048 + l) * 64 + d) = u;
    }
  }
}

// ============================================================================
// qrel[bh][i][r] = sum_d Q[bh][i][d] * rel[r][d], row stride NREL_PAD. fp32.
// Reads bf16 Q (row-major [bh][l][64]); one block per (i-tile, bh).
// ============================================================================
__global__ __launch_bounds__(256) void qrel_kernel(const ushort* __restrict__ Qw,
                                                   const float* __restrict__ rel,
                                                   float* __restrict__ qrel) {
  __shared__ float Qs[64][68];  // [i][d] fp32 (converted)
  __shared__ float Rs[64][68];  // [d][r] (transposed rel tile)
  const int t = threadIdx.x;
  const int tx = t & 15, ty = t >> 4;
  const int i0 = blockIdx.x * 64;
  const int bh = blockIdx.y;
  const ushort* Qb = Qw + (size_t)bh * 2048 * 64;
#pragma unroll
  for (int s = 0; s < 2; ++s) {
    int c = t + s * 256;            // 512 chunks of 8 bf16
    int row = c >> 3, off = (c & 7) << 3;
    uint4 raw = *(const uint4*)(Qb + (size_t)(i0 + row) * 64 + off);
    const ushort* rp = (const ushort*)&raw;
    *(float4*)&Qs[row][off] =
        make_float4(bf2f(rp[0]), bf2f(rp[1]), bf2f(rp[2]), bf2f(rp[3]));
    *(float4*)&Qs[row][off + 4] =
        make_float4(bf2f(rp[4]), bf2f(rp[5]), bf2f(rp[6]), bf2f(rp[7]));
  }
  for (int r0 = 0; r0 < 512; r0 += 64) {
    __syncthreads();  // prev Rs readers done (covers Qs staging 1st time)
#pragma unroll
    for (int s = 0; s < 4; ++s) {
      int idx = t + s * 256;
      int rr = idx >> 4;
      int c4 = (idx & 15) << 2;
      int rc = min(r0 + rr, NREL - 1);
      float4 g = *(const float4*)(rel + (size_t)rc * 64 + c4);
      Rs[c4 + 0][rr] = g.x; Rs[c4 + 1][rr] = g.y;
      Rs[c4 + 2][rr] = g.z; Rs[c4 + 3][rr] = g.w;
    }
    __syncthreads();
    float acc[4][4] = {};
#pragma unroll
    for (int d = 0; d < 64; ++d) {
      float4 b4 = *(const float4*)&Rs[d][tx << 2];
      float bv[4] = {b4.x, b4.y, b4.z, b4.w};
      float av[4] = {Qs[(ty << 2) + 0][d], Qs[(ty << 2) + 1][d],
                     Qs[(ty << 2) + 2][d], Qs[(ty << 2) + 3][d]};
#pragma unroll
      for (int ii = 0; ii < 4; ++ii)
#pragma unroll
        for (int jj = 0; jj < 4; ++jj) acc[ii][jj] += av[ii] * bv[jj];
    }
    int r = r0 + (tx << 2);
    if (r <= NREL_PAD - 4) {
#pragma unroll
      for (int ii = 0; ii < 4; ++ii) {
        int i = i0 + (ty << 2) + ii;
        float4 o = make_float4(acc[ii][0], acc[ii][1], acc[ii][2], acc[ii][3]);
        *(float4*)(qrel + ((size_t)bh * 2048 + i) * NREL_PAD + r) = o;
      }
    }
  }
}

// ============================================================================
// Flash attention, MFMA bf16. One block = (i-tile 64, bh), 4 waves; wave w
// owns i-strip w*16..w*16+15. Loops 32 j-tiles of 64.
// S = (Q Kt)/8 + qrel bias, mask, online softmax (C-layout), P->LDS (wave-
// private strip, no barrier), O += P V. Ps overlays Qs.
// ============================================================================
__global__ __launch_bounds__(256) void flash_attn(
    const ushort* __restrict__ Qw, const ushort* __restrict__ Kw,
    const ushort* __restrict__ Vt, const float* __restrict__ qrel,
    const int* __restrict__ mask, float* __restrict__ attn) {
  __shared__ ushort QPs[64 * LDB];  // Q tile [i][d]; later P [i][j]
  __shared__ ushort Ks[64 * LDB];   // [j][d]
  __shared__ ushort Vs[64 * LDB];   // [d][j]
  const int t = threadIdx.x;
  const int lane = t & 63, wave = t >> 6;
  const int m16 = lane & 15, quad = lane >> 4;
  const int koff = quad << 3;       // 0,8,16,24
  const int i0 = blockIdx.x * 64;
  const int bh = blockIdx.y;
  const int b = bh >> 3, h = bh & 7;
  const ushort* Qb = Qw + (size_t)bh * 2048 * 64;
  const ushort* Kb = Kw + (size_t)bh * 2048 * 64;
  const ushort* Vb = Vt + (size_t)bh * 64 * 2048;
  const float* qrl = qrel + (size_t)bh * 2048 * NREL_PAD;
  const int* mb = mask + b * 2048;

  // stage Q tile [i][d]
#pragma unroll
  for (int s = 0; s < 2; ++s) {
    int c = t + s * 256;            // 512 chunks of 8 bf16
    int row = c >> 3, off = (c & 7) << 3;
    *(uint4*)&QPs[row * LDB + off] =
        *(const uint4*)(Qb + (size_t)(i0 + row) * 64 + off);
  }
  __syncthreads();

  // Q A-fragments (j-invariant): rows wave*16+m16, k halves 0/1
  bf16x8 qa0 = *(const bf16x8*)&QPs[((wave << 4) + m16) * LDB + koff];
  bf16x8 qa1 = *(const bf16x8*)&QPs[((wave << 4) + m16) * LDB + 32 + koff];

  float m_i[4], l_i[4];
  f32x4 oacc[4];
#pragma unroll
  for (int r = 0; r < 4; ++r) { m_i[r] = -INFINITY; l_i[r] = 0.f; }
#pragma unroll
  for (int dt = 0; dt < 4; ++dt) oacc[dt] = (f32x4){0.f, 0.f, 0.f, 0.f};

  const int irow0 = i0 + (wave << 4) + (quad << 2);  // this lane's 4 rows

  for (int j0 = 0; j0 < 2048; j0 += 64) {
    __syncthreads();  // prev-iter Ks/Vs readers + QPs(P) readers done
#pragma unroll
    for (int s = 0; s < 2; ++s) {
      int c = t + s * 256;
      int row = c >> 3, off = (c & 7) << 3;
      *(uint4*)&Ks[row * LDB + off] =
          *(const uint4*)(Kb + (size_t)(j0 + row) * 64 + off);
      *(uint4*)&Vs[row * LDB + off] =
          *(const uint4*)(Vb + (size_t)row * 2048 + j0 + off);
    }
    __syncthreads();

    // S = Q Kt  (rows: this wave's strip; cols: 4 j-subtiles of 16)
    f32x4 sacc[4];
#pragma unroll
    for (int jt = 0; jt < 4; ++jt) {
      bf16x8 kb0 = *(const bf16x8*)&Ks[((jt << 4) + m16) * LDB + koff];
      bf16x8 kb1 = *(const bf16x8*)&Ks[((jt << 4) + m16) * LDB + 32 + koff];
      f32x4 z = {0.f, 0.f, 0.f, 0.f};
      z = __builtin_amdgcn_mfma_f32_16x16x32_bf16(qa0, kb0, z, 0, 0, 0);
      z = __builtin_amdgcn_mfma_f32_16x16x32_bf16(qa1, kb1, z, 0, 0, 0);
      sacc[jt] = z;
    }

    // bias + mask (C-layout: row = quad*4+r, col = jt*16+m16)
    float sv[4][4];
    int mk[4];
#pragma unroll
    for (int jt = 0; jt < 4; ++jt) mk[jt] = mb[j0 + (jt << 4) + m16];
#pragma unroll
    for (int jt = 0; jt < 4; ++jt) {
      int j = j0 + (jt << 4) + m16;
#pragma unroll
      for (int r = 0; r < 4; ++r) {
        int i = irow0 + r;
        int rr = min(NREL - 1, max(0, j - i + (NREL / 2)));
        float sc = sacc[jt][r] * 0.125f + qrl[(size_t)i * NREL_PAD + rr];
        sv[jt][r] = (mk[jt] == 0) ? -1e10f : sc;
      }
    }

    // online softmax per row r (reduce over 16 lanes of the quad + 4 jt)
    float al[4];
#pragma unroll
    for (int r = 0; r < 4; ++r) {
      float mx = fmaxf(fmaxf(sv[0][r], sv[1][r]), fmaxf(sv[2][r], sv[3][r]));
#pragma unroll
      for (int w = 1; w < 16; w <<= 1) mx = fmaxf(mx, __shfl_xor(mx, w, 16));
      float mnew = fmaxf(m_i[r], mx);
      al[r] = __expf(m_i[r] - mnew);
      float sum = 0.f;
#pragma unroll
      for (int jt = 0; jt < 4; ++jt) {
        float p = __expf(sv[jt][r] - mnew);
        sv[jt][r] = p;
        sum += p;
      }
#pragma unroll
      for (int w = 1; w < 16; w <<= 1) sum += __shfl_xor(sum, w, 16);
      m_i[r] = mnew;
      l_i[r] = l_i[r] * al[r] + sum;
#pragma unroll
      for (int dt = 0; dt < 4; ++dt) oacc[dt][r] *= al[r];
    }

    // P -> LDS (bf16), wave-private 16-row strip of QPs; then A-frag reads.
    const int prow0 = (wave << 4) + (quad << 2);
#pragma unroll
    for (int jt = 0; jt < 4; ++jt)
#pragma unroll
      for (int r = 0; r < 4; ++r)
        QPs[(prow0 + r) * LDB + (jt << 4) + m16] = f2bf(sv[jt][r]);
    __asm__ volatile("s_waitcnt lgkmcnt(0)" ::: "memory");  // wave-local drain

    bf16x8 pa0 = *(const bf16x8*)&QPs[((wave << 4) + m16) * LDB + koff];
    bf16x8 pa1 = *(const bf16x8*)&QPs[((wave << 4) + m16) * LDB + 32 + koff];
#pragma unroll
    for (int dt = 0; dt < 4; ++dt) {
      bf16x8 vb0 = *(const bf16x8*)&Vs[((dt << 4) + m16) * LDB + koff];
      bf16x8 vb1 = *(const bf16x8*)&Vs[((dt << 4) + m16) * LDB + 32 + koff];
      oacc[dt] = __builtin_amdgcn_mfma_f32_16x16x32_bf16(pa0, vb0, oacc[dt], 0, 0, 0);
      oacc[dt] = __builtin_amdgcn_mfma_f32_16x16x32_bf16(pa1, vb1, oacc[dt], 0, 0, 0);
    }
  }

  // normalize + write attn[b][i][h*64 + d]  (C-layout cols d = dt*16+m16)
#pragma unroll
  for (int r = 0; r < 4; ++r) {
    float inv = 1.0f / l_i[r];
    int i = irow0 + r;
    float* dst = attn + (size_t)(b * 2048 + i) * 512 + h * 64;
#pragma unroll
    for (int dt = 0; dt < 4; ++dt) dst[(dt << 4) + m16] = oacc[dt][r] * inv;
  }
}

// ============================================================================
extern "C" void kernel_launch(void* const* d_in, const int* in_sizes, int n_in,
                              void* d_out, int out_size, void* d_ws,
                              size_t ws_size, hipStream_t stream) {
  const float* query = (const float*)d_in[0];
  const float* key   = (const float*)d_in[1];
  const float* value = (const float*)d_in[2];
  const int*   mask  = (const int*)d_in[3];
  const float* Wq = (const float*)d_in[4];
  const float* bq = (const float*)d_in[5];
  const float* Wk = (const float*)d_in[6];
  const float* bk = (const float*)d_in[7];
  const float* Wv = (const float*)d_in[8];
  const float* bv = (const float*)d_in[9];
  const float* Wo = (const float*)d_in[10];
  const float* bo = (const float*)d_in[11];
  const float* rel = (const float*)d_in[12];

  char* w = (char*)d_ws;
  ushort* Qw  = (ushort*)w; w += (size_t)16 * 2048 * 64 * 2;       // 4 MB
  ushort* Kw  = (ushort*)w; w += (size_t)16 * 2048 * 64 * 2;       // 4 MB
  ushort* Vtw = (ushort*)w; w += (size_t)16 * 64 * 2048 * 2;       // 4 MB
  float* qrel = (float*)w;  w += (size_t)16 * 2048 * NREL_PAD * 4; // 65.5 MB
  float* attn = (float*)w;                                         // 8 MB
  float* out = (float*)d_out;

  dim3 bb(256);
  dim3 gg(8, 64);
  hipLaunchKernelGGL((gemm512<2>), gg, bb, 0, stream, query, Wq, bq, (void*)Qw);
  hipLaunchKernelGGL((gemm512<2>), gg, bb, 0, stream, key, Wk, bk, (void*)Kw);
  hipLaunchKernelGGL((gemm512<1>), gg, bb, 0, stream, value, Wv, bv, (void*)Vtw);
  hipLaunchKernelGGL(qrel_kernel, dim3(32, 16), bb, 0, stream, Qw, rel, qrel);
  hipLaunchKernelGGL(flash_attn, dim3(32, 16), bb, 0, stream, Qw, Kw, Vtw, qrel,
                     mask, attn);
  hipLaunchKernelGGL((gemm512<0>), gg, bb, 0, stream, attn, Wo, bo, (void*)out);
}

// Round 4
// 402.106 us; speedup vs baseline: 3.2558x; 1.0841x over previous
//
#include <hip/hip_runtime.h>
#include <math.h>

// Problem constants
#define NREL 499        // 2*MAX_LEN-1
#define NREL_PAD 500    // row stride for qrel (2000 B, 16-B aligned)
#define LDB 72          // bf16 LDS row stride (flash kernel)

typedef __attribute__((ext_vector_type(8))) short bf16x8;
typedef __attribute__((ext_vector_type(4))) float f32x4;

__device__ __forceinline__ float bf2f(ushort x) {
  union { unsigned u; float f; } v; v.u = ((unsigned)x) << 16; return v.f;
}
__device__ __forceinline__ ushort f2bf(float x) {
  union { float f; unsigned u; } v; v.f = x;
  return (ushort)((v.u + 0x8000u) >> 16);
}
__device__ __forceinline__ bf16x8 pack8(float4 a, float4 b) {
  bf16x8 r;
  r[0] = (short)f2bf(a.x); r[1] = (short)f2bf(a.y);
  r[2] = (short)f2bf(a.z); r[3] = (short)f2bf(a.w);
  r[4] = (short)f2bf(b.x); r[5] = (short)f2bf(b.y);
  r[6] = (short)f2bf(b.z); r[7] = (short)f2bf(b.w);
  return r;
}

// ============================================================================
// prep_wt: Wt[z][n][k] (bf16) = W_z[k][n], z = {q,k,v,o}. Grid (8,8,4).
// ============================================================================
__global__ __launch_bounds__(256) void prep_wt(const float* __restrict__ W0,
                                               const float* __restrict__ W1,
                                               const float* __restrict__ W2,
                                               const float* __restrict__ W3,
                                               ushort* __restrict__ Wt) {
  __shared__ float T[64][68];
  const int t = threadIdx.x;
  const int k0 = blockIdx.x * 64, n0 = blockIdx.y * 64, z = blockIdx.z;
  const float* W = (z == 0) ? W0 : (z == 1) ? W1 : (z == 2) ? W2 : W3;
#pragma unroll
  for (int s = 0; s < 4; ++s) {
    int idx = t + s * 256;
    int r = idx >> 4, c4 = (idx & 15) << 2;
    *(float4*)&T[r][c4] = *(const float4*)(W + (size_t)(k0 + r) * 512 + n0 + c4);
  }
  __syncthreads();
#pragma unroll
  for (int s = 0; s < 4; ++s) {
    int idx = t + s * 256;
    int row = idx >> 4, c4 = (idx & 15) << 2;  // row = n_local, c4 = k_local
    ushort4 u = make_ushort4(f2bf(T[c4 + 0][row]), f2bf(T[c4 + 1][row]),
                             f2bf(T[c4 + 2][row]), f2bf(T[c4 + 3][row]));
    *(ushort4*)(Wt + (size_t)z * 262144 + (size_t)(n0 + row) * 512 + k0 + c4) = u;
  }
}

// ============================================================================
// gemm_mfma: C[4096x512] = A(fp32) @ Wt^T(bf16 [n][k]) + bias. No LDS; A/W
// fragments straight from global (Wt L2-resident). Tile 64x64, 4 waves.
// MODE 0: fp32 row-major out [4096][512]               (output projection)
// MODE 1: bf16 Vt [bh][64 d][2048 l] (operands swapped -> coalesced stores)
// MODE 2: bf16 row-major head-split [bh][2048 l][64 d] (Q, K)
// ============================================================================
template <int MODE>
__global__ __launch_bounds__(256) void gemm_mfma(const float* __restrict__ A,
                                                 const ushort* __restrict__ Wt,
                                                 const float* __restrict__ bias,
                                                 void* __restrict__ outv) {
  const int t = threadIdx.x;
  const int lane = t & 63, wave = t >> 6;
  const int m16 = lane & 15, quad = lane >> 4;
  const int i0 = blockIdx.y * 64;
  const int n0 = blockIdx.x * 64;
  f32x4 acc[4] = {{0.f, 0.f, 0.f, 0.f}, {0.f, 0.f, 0.f, 0.f},
                  {0.f, 0.f, 0.f, 0.f}, {0.f, 0.f, 0.f, 0.f}};

  if (MODE != 1) {
    // D rows = i (wave strip), cols = n. acc[nt]: n-subtile nt.
    const float* arow = A + (size_t)(i0 + (wave << 4) + m16) * 512 + (quad << 3);
#pragma unroll 4
    for (int kc = 0; kc < 16; ++kc) {
      float4 a0 = *(const float4*)(arow + kc * 32);
      float4 a1 = *(const float4*)(arow + kc * 32 + 4);
      bf16x8 af = pack8(a0, a1);
#pragma unroll
      for (int nt = 0; nt < 4; ++nt) {
        bf16x8 wf = *(const bf16x8*)(Wt + (size_t)(n0 + (nt << 4) + m16) * 512 +
                                     kc * 32 + (quad << 3));
        acc[nt] = __builtin_amdgcn_mfma_f32_16x16x32_bf16(af, wf, acc[nt], 0, 0, 0);
      }
    }
  } else {
    // D rows = n (wave strip), cols = i. acc[it]: i-subtile it.
    const ushort* wrow = Wt + (size_t)(n0 + (wave << 4) + m16) * 512 + (quad << 3);
#pragma unroll 2
    for (int kc = 0; kc < 16; ++kc) {
      bf16x8 wf = *(const bf16x8*)(wrow + kc * 32);
#pragma unroll
      for (int it = 0; it < 4; ++it) {
        const float* ap = A + (size_t)(i0 + (it << 4) + m16) * 512 + kc * 32 + (quad << 3);
        bf16x8 af = pack8(*(const float4*)ap, *(const float4*)(ap + 4));
        acc[it] = __builtin_amdgcn_mfma_f32_16x16x32_bf16(wf, af, acc[it], 0, 0, 0);
      }
    }
  }

  if (MODE == 0) {
    float* out = (float*)outv;
#pragma unroll
    for (int nt = 0; nt < 4; ++nt) {
      float bn = bias[n0 + (nt << 4) + m16];
#pragma unroll
      for (int r = 0; r < 4; ++r) {
        int i = i0 + (wave << 4) + (quad << 2) + r;
        out[(size_t)i * 512 + n0 + (nt << 4) + m16] = acc[nt][r] + bn;
      }
    }
  } else if (MODE == 2) {
    ushort* out = (ushort*)outv;
    const int b = i0 >> 11, l0 = i0 & 2047, h = n0 >> 6;
#pragma unroll
    for (int nt = 0; nt < 4; ++nt) {
      float bn = bias[n0 + (nt << 4) + m16];
      int d = (nt << 4) + m16;
#pragma unroll
      for (int r = 0; r < 4; ++r) {
        int il = (wave << 4) + (quad << 2) + r;
        out[((size_t)(b * 8 + h) * 2048 + l0 + il) * 64 + d] = f2bf(acc[nt][r] + bn);
      }
    }
  } else {  // MODE 1: Vt [bh][d][l]
    ushort* out = (ushort*)outv;
    const int b = i0 >> 11, l0 = i0 & 2047, h = n0 >> 6;
    float4 b4 = *(const float4*)(bias + n0 + (wave << 4) + (quad << 2));
    float bb[4] = {b4.x, b4.y, b4.z, b4.w};
#pragma unroll
    for (int r = 0; r < 4; ++r) {
      int d = (wave << 4) + (quad << 2) + r;
#pragma unroll
      for (int it = 0; it < 4; ++it) {
        out[((size_t)(b * 8 + h) * 64 + d) * 2048 + l0 + (it << 4) + m16] =
            f2bf(acc[it][r] + bb[r]);
      }
    }
  }
}

// ============================================================================
// qrel_mfma: qrel[bh][i][r] = sum_d Q[bh][i][d]*rel[r][d] (fp32 out, stride
// NREL_PAD). MFMA bf16, fragments direct from global. Grid (8, 32, 16).
// ============================================================================
__global__ __launch_bounds__(256) void qrel_mfma(const ushort* __restrict__ Qw,
                                                 const float* __restrict__ rel,
                                                 float* __restrict__ qrel) {
  const int t = threadIdx.x;
  const int lane = t & 63, wave = t >> 6;
  const int m16 = lane & 15, quad = lane >> 4;
  const int r0 = blockIdx.x * 64;
  const int i0 = blockIdx.y * 64;
  const int bh = blockIdx.z;
  const ushort* Qb = Qw + ((size_t)bh * 2048 + i0 + (wave << 4) + m16) * 64;
  bf16x8 qa0 = *(const bf16x8*)(Qb + (quad << 3));
  bf16x8 qa1 = *(const bf16x8*)(Qb + 32 + (quad << 3));

  f32x4 acc[4] = {{0.f, 0.f, 0.f, 0.f}, {0.f, 0.f, 0.f, 0.f},
                  {0.f, 0.f, 0.f, 0.f}, {0.f, 0.f, 0.f, 0.f}};
#pragma unroll
  for (int rt = 0; rt < 4; ++rt) {
    int rr = min(r0 + (rt << 4) + m16, NREL - 1);
    const float* rp = rel + (size_t)rr * 64 + (quad << 3);
    bf16x8 rf0 = pack8(*(const float4*)rp, *(const float4*)(rp + 4));
    bf16x8 rf1 = pack8(*(const float4*)(rp + 32), *(const float4*)(rp + 36));
    acc[rt] = __builtin_amdgcn_mfma_f32_16x16x32_bf16(qa0, rf0, acc[rt], 0, 0, 0);
    acc[rt] = __builtin_amdgcn_mfma_f32_16x16x32_bf16(qa1, rf1, acc[rt], 0, 0, 0);
  }
#pragma unroll
  for (int rt = 0; rt < 4; ++rt) {
    int r = r0 + (rt << 4) + m16;
    if (r < NREL_PAD) {
#pragma unroll
      for (int rg = 0; rg < 4; ++rg) {
        int i = i0 + (wave << 4) + (quad << 2) + rg;
        qrel[((size_t)bh * 2048 + i) * NREL_PAD + r] = acc[rt][rg];
      }
    }
  }
}

// ============================================================================
// Flash attention, MFMA bf16 (unchanged from R2).
// ============================================================================
__global__ __launch_bounds__(256) void flash_attn(
    const ushort* __restrict__ Qw, const ushort* __restrict__ Kw,
    const ushort* __restrict__ Vt, const float* __restrict__ qrel,
    const int* __restrict__ mask, float* __restrict__ attn) {
  __shared__ ushort QPs[64 * LDB];  // Q tile [i][d]; later P [i][j]
  __shared__ ushort Ks[64 * LDB];   // [j][d]
  __shared__ ushort Vs[64 * LDB];   // [d][j]
  const int t = threadIdx.x;
  const int lane = t & 63, wave = t >> 6;
  const int m16 = lane & 15, quad = lane >> 4;
  const int koff = quad << 3;
  const int i0 = blockIdx.x * 64;
  const int bh = blockIdx.y;
  const int b = bh >> 3, h = bh & 7;
  const ushort* Qb = Qw + (size_t)bh * 2048 * 64;
  const ushort* Kb = Kw + (size_t)bh * 2048 * 64;
  const ushort* Vb = Vt + (size_t)bh * 64 * 2048;
  const float* qrl = qrel + (size_t)bh * 2048 * NREL_PAD;
  const int* mb = mask + b * 2048;

#pragma unroll
  for (int s = 0; s < 2; ++s) {
    int c = t + s * 256;
    int row = c >> 3, off = (c & 7) << 3;
    *(uint4*)&QPs[row * LDB + off] =
        *(const uint4*)(Qb + (size_t)(i0 + row) * 64 + off);
  }
  __syncthreads();

  bf16x8 qa0 = *(const bf16x8*)&QPs[((wave << 4) + m16) * LDB + koff];
  bf16x8 qa1 = *(const bf16x8*)&QPs[((wave << 4) + m16) * LDB + 32 + koff];

  float m_i[4], l_i[4];
  f32x4 oacc[4];
#pragma unroll
  for (int r = 0; r < 4; ++r) { m_i[r] = -INFINITY; l_i[r] = 0.f; }
#pragma unroll
  for (int dt = 0; dt < 4; ++dt) oacc[dt] = (f32x4){0.f, 0.f, 0.f, 0.f};

  const int irow0 = i0 + (wave << 4) + (quad << 2);

  for (int j0 = 0; j0 < 2048; j0 += 64) {
    __syncthreads();
#pragma unroll
    for (int s = 0; s < 2; ++s) {
      int c = t + s * 256;
      int row = c >> 3, off = (c & 7) << 3;
      *(uint4*)&Ks[row * LDB + off] =
          *(const uint4*)(Kb + (size_t)(j0 + row) * 64 + off);
      *(uint4*)&Vs[row * LDB + off] =
          *(const uint4*)(Vb + (size_t)row * 2048 + j0 + off);
    }
    __syncthreads();

    f32x4 sacc[4];
#pragma unroll
    for (int jt = 0; jt < 4; ++jt) {
      bf16x8 kb0 = *(const bf16x8*)&Ks[((jt << 4) + m16) * LDB + koff];
      bf16x8 kb1 = *(const bf16x8*)&Ks[((jt << 4) + m16) * LDB + 32 + koff];
      f32x4 z = {0.f, 0.f, 0.f, 0.f};
      z = __builtin_amdgcn_mfma_f32_16x16x32_bf16(qa0, kb0, z, 0, 0, 0);
      z = __builtin_amdgcn_mfma_f32_16x16x32_bf16(qa1, kb1, z, 0, 0, 0);
      sacc[jt] = z;
    }

    float sv[4][4];
    int mk[4];
#pragma unroll
    for (int jt = 0; jt < 4; ++jt) mk[jt] = mb[j0 + (jt << 4) + m16];
#pragma unroll
    for (int jt = 0; jt < 4; ++jt) {
      int j = j0 + (jt << 4) + m16;
#pragma unroll
      for (int r = 0; r < 4; ++r) {
        int i = irow0 + r;
        int rr = min(NREL - 1, max(0, j - i + (NREL / 2)));
        float sc = sacc[jt][r] * 0.125f + qrl[(size_t)i * NREL_PAD + rr];
        sv[jt][r] = (mk[jt] == 0) ? -1e10f : sc;
      }
    }

    float al[4];
#pragma unroll
    for (int r = 0; r < 4; ++r) {
      float mx = fmaxf(fmaxf(sv[0][r], sv[1][r]), fmaxf(sv[2][r], sv[3][r]));
#pragma unroll
      for (int w = 1; w < 16; w <<= 1) mx = fmaxf(mx, __shfl_xor(mx, w, 16));
      float mnew = fmaxf(m_i[r], mx);
      al[r] = __expf(m_i[r] - mnew);
      float sum = 0.f;
#pragma unroll
      for (int jt = 0; jt < 4; ++jt) {
        float p = __expf(sv[jt][r] - mnew);
        sv[jt][r] = p;
        sum += p;
      }
#pragma unroll
      for (int w = 1; w < 16; w <<= 1) sum += __shfl_xor(sum, w, 16);
      m_i[r] = mnew;
      l_i[r] = l_i[r] * al[r] + sum;
#pragma unroll
      for (int dt = 0; dt < 4; ++dt) oacc[dt][r] *= al[r];
    }

    const int prow0 = (wave << 4) + (quad << 2);
#pragma unroll
    for (int jt = 0; jt < 4; ++jt)
#pragma unroll
      for (int r = 0; r < 4; ++r)
        QPs[(prow0 + r) * LDB + (jt << 4) + m16] = f2bf(sv[jt][r]);
    __asm__ volatile("s_waitcnt lgkmcnt(0)" ::: "memory");

    bf16x8 pa0 = *(const bf16x8*)&QPs[((wave << 4) + m16) * LDB + koff];
    bf16x8 pa1 = *(const bf16x8*)&QPs[((wave << 4) + m16) * LDB + 32 + koff];
#pragma unroll
    for (int dt = 0; dt < 4; ++dt) {
      bf16x8 vb0 = *(const bf16x8*)&Vs[((dt << 4) + m16) * LDB + koff];
      bf16x8 vb1 = *(const bf16x8*)&Vs[((dt << 4) + m16) * LDB + 32 + koff];
      oacc[dt] = __builtin_amdgcn_mfma_f32_16x16x32_bf16(pa0, vb0, oacc[dt], 0, 0, 0);
      oacc[dt] = __builtin_amdgcn_mfma_f32_16x16x32_bf16(pa1, vb1, oacc[dt], 0, 0, 0);
    }
  }

#pragma unroll
  for (int r = 0; r < 4; ++r) {
    float inv = 1.0f / l_i[r];
    int i = irow0 + r;
    float* dst = attn + (size_t)(b * 2048 + i) * 512 + h * 64;
#pragma unroll
    for (int dt = 0; dt < 4; ++dt) dst[(dt << 4) + m16] = oacc[dt][r] * inv;
  }
}

// ============================================================================
extern "C" void kernel_launch(void* const* d_in, const int* in_sizes, int n_in,
                              void* d_out, int out_size, void* d_ws,
                              size_t ws_size, hipStream_t stream) {
  const float* query = (const float*)d_in[0];
  const float* key   = (const float*)d_in[1];
  const float* value = (const float*)d_in[2];
  const int*   mask  = (const int*)d_in[3];
  const float* Wq = (const float*)d_in[4];
  const float* bq = (const float*)d_in[5];
  const float* Wk = (const float*)d_in[6];
  const float* bk = (const float*)d_in[7];
  const float* Wv = (const float*)d_in[8];
  const float* bv = (const float*)d_in[9];
  const float* Wo = (const float*)d_in[10];
  const float* bo = (const float*)d_in[11];
  const float* rel = (const float*)d_in[12];

  char* w = (char*)d_ws;
  ushort* Qw  = (ushort*)w; w += (size_t)16 * 2048 * 64 * 2;       // 4 MB
  ushort* Kw  = (ushort*)w; w += (size_t)16 * 2048 * 64 * 2;       // 4 MB
  ushort* Vtw = (ushort*)w; w += (size_t)16 * 64 * 2048 * 2;       // 4 MB
  ushort* Wt  = (ushort*)w; w += (size_t)4 * 512 * 512 * 2;        // 2 MB
  float* qrel = (float*)w;  w += (size_t)16 * 2048 * NREL_PAD * 4; // 65.5 MB
  float* attn = (float*)w;                                         // 8 MB
  float* out = (float*)d_out;

  dim3 bb(256);
  dim3 gg(8, 64);
  hipLaunchKernelGGL(prep_wt, dim3(8, 8, 4), bb, 0, stream, Wq, Wk, Wv, Wo, Wt);
  hipLaunchKernelGGL((gemm_mfma<2>), gg, bb, 0, stream, query, Wt + 0 * 262144, bq, (void*)Qw);
  hipLaunchKernelGGL((gemm_mfma<2>), gg, bb, 0, stream, key, Wt + 1 * 262144, bk, (void*)Kw);
  hipLaunchKernelGGL((gemm_mfma<1>), gg, bb, 0, stream, value, Wt + 2 * 262144, bv, (void*)Vtw);
  hipLaunchKernelGGL(qrel_mfma, dim3(8, 32, 16), bb, 0, stream, Qw, rel, qrel);
  hipLaunchKernelGGL(flash_attn, dim3(32, 16), bb, 0, stream, Qw, Kw, Vtw, qrel,
                     mask, attn);
  hipLaunchKernelGGL((gemm_mfma<0>), gg, bb, 0, stream, attn, Wt + 3 * 262144, bo, (void*)out);
}